// Round 2
// baseline (179.527 us; speedup 1.0000x reference)
//
#include <hip/hip_runtime.h>

// Problem constants
#define BATCH   32
#define CIN     256
#define COUT    64
#define HW      1024          // 32*32
#define NE      1024          // codebook size
#define ED      64            // code dim
#define NROW    32768         // BATCH*COUT*HW/ED
#define ZTOT    2097152       // BATCH*COUT*HW

// d_out layout (floats): z_q_st[ZTOT], loss[1], sampled[32768], min_idx[32768]
#define OFF_LOSS 2097152
#define OFF_SAMP 2097153
#define OFF_IDX  2129921

// LDS strides (floats). Pad +4 words keeps b128 staging writes bank-balanced
// (stride%32==4 -> 8 words/bank per wave instr = conflict-free floor).
#define CXSTR 132   // conv Xs [64 c][128 px]
#define CWSTR 68    // conv Ws [64 c][64 o]
#define ZSTR  132   // dist zs [64 k][128 rows]
#define ESTR2 260   // dist es [64 k][256 codes]

// ---------------------------------------------------------------------------
// k_pre: one launch fusing (a) sampled zeroing, (b) contrastive partials with
// block-local inv-norms, (c) enorm for k_dist, (d) the 1x1 conv.
// Prep blocks come FIRST so they co-schedule under the conv blocks.
// blocks 0..127   : zero out_samp
// blocks 128..143 : contrast partial (self-computed invn, bit-identical)
// blocks 144..147 : enorm
// blocks 148..403 : conv, 128px x 64out tile (8px x 4o per thread)
__global__ __launch_bounds__(256, 2) void k_pre(const float* __restrict__ x,
                                                const float* __restrict__ w,
                                                const float* __restrict__ bias,
                                                float* __restrict__ z,
                                                const float* __restrict__ emb,
                                                float* __restrict__ out_samp,
                                                float* __restrict__ enorm,
                                                float* __restrict__ cpart) {
    __shared__ float SH[64 * CXSTR + 64 * CWSTR];   // 51.2 KB, aliased per branch
    int bx = blockIdx.x;
    int t  = threadIdx.x;

    if (bx < 128) {                       // ---- zero sampled
        out_samp[bx * 256 + t] = 0.0f;
        return;
    }
    if (bx < 144) {                       // ---- contrast partial (16 blocks)
        float* invl = SH;                 // [64]
        float* S    = SH + 64;            // [256]
        int b2 = bx - 128;
        int i0 = b2 * 64;
        if (t < 64) {
            const float* e = emb + (size_t)(i0 + t) * ED;
            float r8[8];
            #pragma unroll
            for (int s = 0; s < 8; s++) { float xx = e[s]; r8[s] = xx * xx; }
            #pragma unroll
            for (int m = 1; m < 8; m++) {
                #pragma unroll
                for (int s = 0; s < 8; s++) { float xx = e[8 * m + s]; r8[s] += xx * xx; }
            }
            float en = ((r8[0] + r8[1]) + (r8[2] + r8[3])) + ((r8[4] + r8[5]) + (r8[6] + r8[7]));
            invl[t] = 1.0f / sqrtf(en);
        }
        __syncthreads();
        int d = t & 63, q = t >> 6;
        float s = 0.0f;
        #pragma unroll
        for (int m = 0; m < 16; m++) {
            int il = q + 4 * m;
            s = fmaf(emb[(size_t)(i0 + il) * ED + d], invl[il], s);
        }
        S[t] = s;
        __syncthreads();
        if (t < 64)
            cpart[b2 * 64 + t] = (S[t] + S[t + 64]) + (S[t + 128] + S[t + 192]);
        return;
    }
    if (bx < 148) {                       // ---- enorm (4 blocks)
        int j = (bx - 144) * 256 + t;     // 0..1023
        const float* e = emb + (size_t)j * ED;
        float r8[8];
        #pragma unroll
        for (int s = 0; s < 8; s++) { float xx = e[s]; r8[s] = xx * xx; }
        #pragma unroll
        for (int m = 1; m < 8; m++) {
            #pragma unroll
            for (int s = 0; s < 8; s++) { float xx = e[8 * m + s]; r8[s] += xx * xx; }
        }
        enorm[j] = ((r8[0] + r8[1]) + (r8[2] + r8[3])) + ((r8[4] + r8[5]) + (r8[6] + r8[7]));
        return;
    }

    // ---- conv: block covers batch b, 128-px tile, all 64 outputs
    float* Xs = SH;                       // [64 c][CXSTR]
    float* Ws = SH + 64 * CXSTR;          // [64 c][CWSTR]
    int cbx = bx - 148;
    int b   = cbx >> 3;                   // 0..31
    int p0  = (cbx & 7) * 128;            // 0..896
    int pg  = t & 15;                     // px: 4*pg+i and 64+4*pg+i
    int og  = t >> 4;                     // o : 4*og+j
    float acc[8][4];
    #pragma unroll
    for (int i = 0; i < 8; i++)
        #pragma unroll
        for (int j = 0; j < 4; j++) acc[i][j] = 0.0f;

    for (int c0 = 0; c0 < CIN; c0 += 64) {
        __syncthreads();
        {
            int u = t & 31, cc = t >> 5;          // Xs stage: 64c x 128px
            #pragma unroll
            for (int m = 0; m < 8; m++) {
                int c = cc + 8 * m;
                float4 v = *(const float4*)&x[(size_t)(b * CIN + c0 + c) * HW + p0 + 4 * u];
                *(float4*)&Xs[c * CXSTR + 4 * u] = v;
            }
            int u2 = t & 15, o2 = t >> 4;         // Ws stage (transposed)
            #pragma unroll
            for (int m = 0; m < 4; m++) {
                int o = o2 + 16 * m;
                float4 v = *(const float4*)&w[o * CIN + c0 + 4 * u2];
                Ws[(4 * u2 + 0) * CWSTR + o] = v.x;
                Ws[(4 * u2 + 1) * CWSTR + o] = v.y;
                Ws[(4 * u2 + 2) * CWSTR + o] = v.z;
                Ws[(4 * u2 + 3) * CWSTR + o] = v.w;
            }
        }
        __syncthreads();
        #pragma unroll 4
        for (int k = 0; k < 64; k++) {
            float4 xa4 = *(const float4*)&Xs[k * CXSTR + 4 * pg];
            float4 xb4 = *(const float4*)&Xs[k * CXSTR + 64 + 4 * pg];
            float4 wv4 = *(const float4*)&Ws[k * CWSTR + 4 * og];
            float xa[8] = {xa4.x, xa4.y, xa4.z, xa4.w, xb4.x, xb4.y, xb4.z, xb4.w};
            float wb[4] = {wv4.x, wv4.y, wv4.z, wv4.w};
            #pragma unroll
            for (int i = 0; i < 8; i++)
                #pragma unroll
                for (int j = 0; j < 4; j++)
                    acc[i][j] = fmaf(xa[i], wb[j], acc[i][j]);
        }
    }
    #pragma unroll
    for (int j = 0; j < 4; j++) {
        int o = 4 * og + j;
        float bv = bias[o];
        float4 lo, hi;
        lo.x = acc[0][j] + bv; lo.y = acc[1][j] + bv;
        lo.z = acc[2][j] + bv; lo.w = acc[3][j] + bv;
        hi.x = acc[4][j] + bv; hi.y = acc[5][j] + bv;
        hi.z = acc[6][j] + bv; hi.w = acc[7][j] + bv;
        *(float4*)&z[(size_t)(b * COUT + o) * HW + p0 + 4 * pg]      = lo;
        *(float4*)&z[(size_t)(b * COUT + o) * HW + p0 + 64 + 4 * pg] = hi;
    }
}

// ---------------------------------------------------------------------------
// k_dist v2: 256 blocks x 256 threads; 128 rows/block; 4 chunks of 256 codes;
// per-thread tile 8 rows (4 low + 4 high, keeps 2-way-free LDS reads) x 16
// codes. Reads/FMA halved vs v1 (6 b128 / 128 fma). All per-(row,code)
// accumulation stays fmaf k-ascending -> distances bit-identical to v1.
// argmin scratch is overlaid on es (dead after last chunk). ~102 KB LDS,
// 1 block/CU.
__global__ __launch_bounds__(256, 1) void k_dist(const float* __restrict__ z,
                                                 const float* __restrict__ emb,
                                                 const float* __restrict__ enorm,
                                                 float* __restrict__ out_idx,
                                                 float* __restrict__ out_samp,
                                                 float* __restrict__ out_zq,
                                                 float* __restrict__ ssep) {
    __shared__ float zs[64 * ZSTR];       // [k][row]   33.8 KB
    __shared__ float es[64 * ESTR2];      // [k][code]  66.6 KB (reused as argmin scratch)
    __shared__ float zn_s[128];
    __shared__ float en_s[256];
    __shared__ float warr[4];
    float* redd_s = es;                   // [16][128] floats
    int*   redj_s = (int*)(es + 2048);    // [16][128] ints
    int*   bj_s   = (int*)(es + 4096);    // [128]
    int t = threadIdx.x;
    int row0 = blockIdx.x * 128;
    int rg = t & 15;     // rows  4*rg+i (i<4) and 64+4*rg+i
    int cg = t >> 4;     // codes 16*cg + j (local)

    // stage zs transposed: zs[k][r] = z[row0+r][k]
    {
        int k = t & 63, wv = t >> 6;
        #pragma unroll
        for (int m = 0; m < 8; m++) {
            int v = wv + 4 * m;           // 0..31
            float4 val;
            val.x = z[(size_t)(row0 + 4 * v + 0) * ED + k];
            val.y = z[(size_t)(row0 + 4 * v + 1) * ED + k];
            val.z = z[(size_t)(row0 + 4 * v + 2) * ED + k];
            val.w = z[(size_t)(row0 + 4 * v + 3) * ED + k];
            *(float4*)&zs[k * ZSTR + 4 * v] = val;
        }
    }
    __syncthreads();
    // zn from LDS copy (bit-identical values), numpy-pairwise order
    if (t < 128) {
        float r8[8];
        #pragma unroll
        for (int s = 0; s < 8; s++) { float xx = zs[s * ZSTR + t]; r8[s] = xx * xx; }
        #pragma unroll
        for (int m = 1; m < 8; m++) {
            #pragma unroll
            for (int s = 0; s < 8; s++) { float xx = zs[(8 * m + s) * ZSTR + t]; r8[s] += xx * xx; }
        }
        zn_s[t] = ((r8[0] + r8[1]) + (r8[2] + r8[3])) + ((r8[4] + r8[5]) + (r8[6] + r8[7]));
    }

    float bestd[8];
    int   bestj[8];
    #pragma unroll
    for (int i = 0; i < 8; i++) { bestd[i] = __builtin_huge_valf(); bestj[i] = 0; }

    for (int ch = 0; ch < 4; ch++) {
        int c0 = ch * 256;
        __syncthreads();   // protect es/en_s from prior-iteration readers (and flush zn_s at ch=0)
        {
            int k = t & 63, wv = t >> 6;
            #pragma unroll
            for (int m = 0; m < 16; m++) {
                int v = wv + 4 * m;       // 0..63
                float4 val;
                val.x = emb[(size_t)(c0 + 4 * v + 0) * ED + k];
                val.y = emb[(size_t)(c0 + 4 * v + 1) * ED + k];
                val.z = emb[(size_t)(c0 + 4 * v + 2) * ED + k];
                val.w = emb[(size_t)(c0 + 4 * v + 3) * ED + k];
                *(float4*)&es[k * ESTR2 + 4 * v] = val;
            }
            if (t < 64) {
                float4 ev4 = *(const float4*)&enorm[c0 + 4 * t];
                *(float4*)&en_s[4 * t] = ev4;
            }
        }
        __syncthreads();

        float acc[8][16];
        #pragma unroll
        for (int i = 0; i < 8; i++)
            #pragma unroll
            for (int j = 0; j < 16; j++) acc[i][j] = 0.0f;

        #pragma unroll 2
        for (int k = 0; k < 64; k++) {
            float4 za = *(const float4*)&zs[k * ZSTR + 4 * rg];
            float4 zb = *(const float4*)&zs[k * ZSTR + 64 + 4 * rg];
            float4 e0 = *(const float4*)&es[k * ESTR2 + 16 * cg];
            float4 e1 = *(const float4*)&es[k * ESTR2 + 16 * cg + 4];
            float4 e2 = *(const float4*)&es[k * ESTR2 + 16 * cg + 8];
            float4 e3 = *(const float4*)&es[k * ESTR2 + 16 * cg + 12];
            float xa[8]  = {za.x, za.y, za.z, za.w, zb.x, zb.y, zb.z, zb.w};
            float eb[16] = {e0.x, e0.y, e0.z, e0.w, e1.x, e1.y, e1.z, e1.w,
                            e2.x, e2.y, e2.z, e2.w, e3.x, e3.y, e3.z, e3.w};
            #pragma unroll
            for (int i = 0; i < 8; i++)
                #pragma unroll
                for (int j = 0; j < 16; j++)
                    acc[i][j] = fmaf(xa[i], eb[j], acc[i][j]);
        }

        // epilogue: d = fl(fl(zn + en) - 2*dot); strict < keeps first index
        #pragma unroll
        for (int i = 0; i < 8; i++) {
            int rl = (i < 4) ? (4 * rg + i) : (64 + 4 * rg + (i - 4));
            float zn = zn_s[rl];
            #pragma unroll
            for (int j = 0; j < 16; j++) {
                int cl = 16 * cg + j;
                float A = zn + en_s[cl];
                float D = A - 2.0f * acc[i][j];
                if (D < bestd[i]) { bestd[i] = D; bestj[i] = c0 + cl; }
            }
        }
    }

    __syncthreads();   // es dead; safe to overlay argmin scratch
    #pragma unroll
    for (int i = 0; i < 8; i++) {
        int rl = (i < 4) ? (4 * rg + i) : (64 + 4 * rg + (i - 4));
        redd_s[cg * 128 + rl] = bestd[i];
        redj_s[cg * 128 + rl] = bestj[i];
    }
    __syncthreads();
    if (t < 128) {
        float bd = __builtin_huge_valf();
        int   bj = 0x7fffffff;
        #pragma unroll
        for (int c = 0; c < 16; c++) {
            float dd = redd_s[c * 128 + t];
            int   jj = redj_s[c * 128 + t];
            if (dd < bd || (dd == bd && jj < bj)) { bd = dd; bj = jj; }
        }
        int rowg = row0 + t;
        bj_s[t]       = bj;
        out_idx[rowg] = (float)bj;              // min_idx as float
        atomicExch(&out_samp[bj], 1.0f);        // scattered, low contention
    }
    __syncthreads();

    // Fused STE epilogue: z from zs (bit-exact), emb gather, SSE partial.
    // thread t: row r = t&127, k-range [32*kq, 32*kq+32)
    {
        int r  = t & 127;
        int kq = t >> 7;
        int bj = bj_s[r];
        const float* er = emb + (size_t)bj * ED + kq * 32;
        float sq = 0.0f;
        #pragma unroll
        for (int m = 0; m < 8; m++) {
            float4 ev = *(const float4*)&er[4 * m];
            int kk = kq * 32 + 4 * m;
            float zv0 = zs[(kk + 0) * ZSTR + r];
            float zv1 = zs[(kk + 1) * ZSTR + r];
            float zv2 = zs[(kk + 2) * ZSTR + r];
            float zv3 = zs[(kk + 3) * ZSTR + r];
            float d0 = ev.x - zv0, d1 = ev.y - zv1, d2 = ev.z - zv2, d3 = ev.w - zv3;
            float4 o4;
            o4.x = zv0 + d0; o4.y = zv1 + d1; o4.z = zv2 + d2; o4.w = zv3 + d3;
            *(float4*)&out_zq[(size_t)(row0 + r) * ED + kk] = o4;
            sq += d0 * d0; sq += d1 * d1; sq += d2 * d2; sq += d3 * d3;
        }
        #pragma unroll
        for (int off = 32; off > 0; off >>= 1) sq += __shfl_down(sq, off, 64);
        if ((t & 63) == 0) warr[t >> 6] = sq;
    }
    __syncthreads();
    if (t == 0)
        ssep[blockIdx.x] = (warr[0] + warr[1]) + (warr[2] + warr[3]);
}

// ---------------------------------------------------------------------------
// k_final: deterministic combine of 256 SSE partials (double tree) and the
// 16x64 contrastive partials; writes the loss scalar.
__global__ __launch_bounds__(256) void k_final(const float* __restrict__ ssep,
                                               const float* __restrict__ cpart,
                                               float* __restrict__ out_loss) {
    __shared__ double SD[256];
    __shared__ float  CS;
    int t = threadIdx.x;
    SD[t] = (double)ssep[t];
    __syncthreads();
    #pragma unroll
    for (int off = 128; off > 0; off >>= 1) {
        if (t < off) SD[t] += SD[t + off];
        __syncthreads();
    }
    if (t < 64) {
        float v = 0.0f;
        #pragma unroll
        for (int m = 0; m < 16; m++) v += cpart[m * 64 + t];
        float sq = v * v;
        #pragma unroll
        for (int off = 32; off > 0; off >>= 1) sq += __shfl_down(sq, off, 64);
        if (t == 0) CS = sq / (1024.0f * 1024.0f);
    }
    __syncthreads();
    if (t == 0) {
        float m = (float)(SD[0] / (double)ZTOT);
        float loss = m + 0.25f * m;         // LEGACY: mse + BETA*mse
        out_loss[0] = loss + CS;
    }
}

// ---------------------------------------------------------------------------
extern "C" void kernel_launch(void* const* d_in, const int* in_sizes, int n_in,
                              void* d_out, int out_size, void* d_ws, size_t ws_size,
                              hipStream_t stream) {
    (void)in_sizes; (void)n_in; (void)out_size; (void)ws_size;
    const float* z_     = (const float*)d_in[0];
    const float* conv_w = (const float*)d_in[1];
    const float* conv_b = (const float*)d_in[2];
    const float* emb    = (const float*)d_in[3];

    float* out      = (float*)d_out;
    float* out_zq   = out;
    float* out_loss = out + OFF_LOSS;
    float* out_samp = out + OFF_SAMP;
    float* out_idx  = out + OFF_IDX;

    char*  ws       = (char*)d_ws;
    float* wz       = (float*)ws;                         // 2M floats (8 MB)
    float* enorm    = (float*)(ws + 8388608);             // 1024
    float* cpart    = (float*)(ws + 8396800);             // 16*64
    float* ssep     = (float*)(ws + 8400896);             // 256

    k_pre  <<<404, 256, 0, stream>>>(z_, conv_w, conv_b, wz, emb, out_samp, enorm, cpart);
    k_dist <<<256, 256, 0, stream>>>(wz, emb, enorm, out_idx, out_samp, out_zq, ssep);
    k_final<<<1,   256, 0, stream>>>(ssep, cpart, out_loss);
}